// Round 6
// baseline (324.005 us; speedup 1.0000x reference)
//
#include <hip/hip_runtime.h>

// HeteroGAT on MI355X. R6:
//   k_prep: [scatter first: 8 edges/thread, int4 loads, batched atomics] +
//           [feat f32->bf16] + [weight transpose via 64x64 LDS tiles]
//   k_gemmb: 16 bf16-MFMA GEMMs; score epilogue via LDS (unchanged from R5)
//   k_agg: 1 wave/dst node, 4 edges/iter (16 lanes/edge), shfl_xor group combine

#define H_ 8
#define D_ 32
#define HD 256
#define NC 10000
#define NS 1024
#define INC 128
#define INS 64
#define ECC 120000
#define ECS 10000
#define ALPHA 0.2f
#define CAP 64

typedef unsigned short u16;
typedef __attribute__((ext_vector_type(8))) short short8;
typedef __attribute__((ext_vector_type(4))) float f32x4;

// ---- ws layout ----
// u16 region (u16 units)
static constexpr size_t WHB_CC = 0;              // 9*NC*HD
static constexpr size_t WHB_CS = 23040000;       // 3*NC*HD
static constexpr size_t WHB_IN = 30720000;       // NS*HD -> end 30982144 u16
// f32 scores (float units)
static constexpr size_t FB0  = 15491072;
static constexpr size_t ASCC = FB0;              // 9*NC*8
static constexpr size_t ADCC = FB0 + 720000;     // 9*NC*8
static constexpr size_t ASCS = FB0 + 1440000;    // 3*NC*8
static constexpr size_t ADCS = FB0 + 1680000;    // 3*NS*8
// bf16 feats + transposed weights (u16 units)
static constexpr size_t FBC  = 34437760;         // 3*NC*128
static constexpr size_t FBS  = 38277760;         // NS*64
static constexpr size_t WTCC = 38343296;         // 9*32768
static constexpr size_t WTCS = 38638208;         // 3*32768
static constexpr size_t WTIN = 38736512;         // 256*64
static constexpr size_t WTN  = 38752896;         // 3*32768 -> end 38851200 u16
// int counters (byte offset)
static constexpr size_t IBYTE = 77702400;        // 93072 ints (9*NC cc, then 3*NS cs)
// u16 slots (byte offset)
static constexpr size_t SBYTE = 78074688;
static constexpr size_t SLOTCS16 = 5760000;      // u16 idx of cs slots (= 90000*64)

static constexpr int TOTE  = 9 * ECC + 3 * ECS;  // 1,110,000
static constexpr int NB_SC = 543;                // ceil(TOTE/8/256)
static constexpr int NB_FT = 3814;
static constexpr int NB_WT = 128;

__device__ __forceinline__ u16 f2b(float f) {
  unsigned u = __float_as_uint(f);
  return (u16)((u + 0x7FFFu + ((u >> 16) & 1u)) >> 16);
}
__device__ __forceinline__ float bl(unsigned u) { return __uint_as_float(u << 16); }
__device__ __forceinline__ float bh(unsigned u) { return __uint_as_float(u & 0xffff0000u); }

// ================= K1: scatter + cvt_feat + cvt_w(LDS transpose) =================
__global__ __launch_bounds__(256) void k_prep(
    const float* f1, const float* f2, const float* f3, const float* fs,
    const float* Wcc, const float* Wcs, const float* Win, const float* Wnode,
    const int* eccs, const int* eccd, const int* ecss, const int* ecsd,
    u16* wsu, int* cnts, u16* slt) {
  __shared__ float Ls[64 * 65];
  int b = blockIdx.x, t = threadIdx.x;
  if (b < NB_SC) {                                 // ---- edge scatter, 8/thread ----
    int i0 = (b * 256 + t) * 8;
    if (i0 >= TOTE) return;
    int dd[8], ss[8], p[8];
    int cbase; size_t sbase;
    if (i0 < 9 * ECC) {
      int r = i0 / ECC;
      int4 d0 = *(const int4*)&eccd[i0]; int4 d1 = *(const int4*)&eccd[i0 + 4];
      int4 s0 = *(const int4*)&eccs[i0]; int4 s1 = *(const int4*)&eccs[i0 + 4];
      dd[0]=d0.x; dd[1]=d0.y; dd[2]=d0.z; dd[3]=d0.w;
      dd[4]=d1.x; dd[5]=d1.y; dd[6]=d1.z; dd[7]=d1.w;
      ss[0]=s0.x; ss[1]=s0.y; ss[2]=s0.z; ss[3]=s0.w;
      ss[4]=s1.x; ss[5]=s1.y; ss[6]=s1.z; ss[7]=s1.w;
      cbase = r * NC; sbase = 0;
    } else {
      int u0 = i0 - 9 * ECC;
      int r = u0 / ECS;
      int4 d0 = *(const int4*)&ecsd[u0]; int4 d1 = *(const int4*)&ecsd[u0 + 4];
      int4 s0 = *(const int4*)&ecss[u0]; int4 s1 = *(const int4*)&ecss[u0 + 4];
      dd[0]=d0.x; dd[1]=d0.y; dd[2]=d0.z; dd[3]=d0.w;
      dd[4]=d1.x; dd[5]=d1.y; dd[6]=d1.z; dd[7]=d1.w;
      ss[0]=s0.x; ss[1]=s0.y; ss[2]=s0.z; ss[3]=s0.w;
      ss[4]=s1.x; ss[5]=s1.y; ss[6]=s1.z; ss[7]=s1.w;
      cbase = 90000 + r * NS; sbase = SLOTCS16 + (size_t)(90000 + r * NS) * 0; // cs slots offset applied below
      sbase = SLOTCS16 - (size_t)90000 * CAP;      // so (cbase+d)*CAP + sbase works uniformly
    }
    #pragma unroll
    for (int q = 0; q < 8; q++) p[q] = atomicAdd(&cnts[cbase + dd[q]], 1);
    #pragma unroll
    for (int q = 0; q < 8; q++)
      if (p[q] < CAP) slt[sbase + ((size_t)(cbase + dd[q])) * CAP + p[q]] = (u16)ss[q];
    return;
  }
  b -= NB_SC;
  if (b < NB_FT) {                                 // ---- f32 -> bf16 feats ----
    const float* src; u16* dst; int idx, n4;
    if (b < 3750) {
      int ty = b / 1250;
      src = (ty == 0) ? f1 : (ty == 1) ? f2 : f3;
      dst = wsu + FBC + (size_t)ty * 1280000;
      idx = (b - ty * 1250) * 256 + t; n4 = 320000;
    } else {
      src = fs; dst = wsu + FBS; idx = (b - 3750) * 256 + t; n4 = 16384;
    }
    if (idx < n4) {
      float4 v = ((const float4*)src)[idx];
      uint2 o;
      o.x = (unsigned)f2b(v.x) | ((unsigned)f2b(v.y) << 16);
      o.y = (unsigned)f2b(v.z) | ((unsigned)f2b(v.w) << 16);
      *(uint2*)(dst + (size_t)idx * 4) = o;
    }
    return;
  }
  b -= NB_FT;                                      // ---- weight transpose, LDS tile ----
  int mat = b >> 3, sub = b & 7;
  int K = (mat == 12) ? INS : INC;
  if (mat == 12 && sub >= 4) return;
  int k0 = (sub >> 2) * 64, n0 = (sub & 3) * 64;
  const float* src; u16* dst;
  if (mat < 9)        { src = Wcc + (size_t)mat * INC * HD;          dst = wsu + WTCC + (size_t)mat * 32768; }
  else if (mat < 12)  { src = Wcs + (size_t)(mat - 9) * INC * HD;    dst = wsu + WTCS + (size_t)(mat - 9) * 32768; }
  else if (mat == 12) { src = Win;                                   dst = wsu + WTIN; }
  else                { src = Wnode + (size_t)(mat - 13) * INC * HD; dst = wsu + WTN + (size_t)(mat - 13) * 32768; }
  #pragma unroll
  for (int it = 0; it < 4; it++) {
    int idx = t + it * 256;
    int r = idx >> 4, c4 = idx & 15;
    float4 v = *(const float4*)&src[(size_t)(k0 + r) * HD + n0 + c4 * 4];
    Ls[r * 65 + c4 * 4 + 0] = v.x; Ls[r * 65 + c4 * 4 + 1] = v.y;
    Ls[r * 65 + c4 * 4 + 2] = v.z; Ls[r * 65 + c4 * 4 + 3] = v.w;
  }
  __syncthreads();
  int n = t >> 2, k8 = (t & 3) * 16;
  unsigned o[8];
  #pragma unroll
  for (int j = 0; j < 8; j++) {
    u16 lo = f2b(Ls[(k8 + 2 * j) * 65 + n]);
    u16 hi = f2b(Ls[(k8 + 2 * j + 1) * 65 + n]);
    o[j] = (unsigned)lo | ((unsigned)hi << 16);
  }
  uint4* dp = (uint4*)&dst[(size_t)(n0 + n) * K + k0 + k8];
  dp[0] = make_uint4(o[0], o[1], o[2], o[3]);
  dp[1] = make_uint4(o[4], o[5], o[6], o[7]);
}

// ================= K2: 16 GEMMs + score epilogue =================
__global__ __launch_bounds__(256, 2) void k_gemmb(
    u16* wsu, float* wsf, const float* bcc, const float* bcs, const float* bin,
    const float* bnode, const float* accv, const float* acsv) {
  __shared__ __align__(16) char smem[69632];
  u16* As = (u16*)smem;
  u16* Bs = (u16*)(smem + 34816);
  int z = blockIdx.z;
  const u16 *A, *Bt; const float* bias; u16* C; int M, K;
  int nrel; float* sout[3]; const float* avec[3]; bool storeC = true;
  if (z < 9) {
    A = wsu + FBC + (size_t)(z / 3) * 1280000; Bt = wsu + WTCC + (size_t)z * 32768;
    bias = bcc + (size_t)z * HD; C = wsu + WHB_CC + (size_t)z * NC * HD; M = NC; K = 128;
    nrel = 1; sout[0] = wsf + ASCC + (size_t)z * NC * H_; avec[0] = accv + (size_t)z * 512;
  } else if (z < 12) {
    int t2 = z - 9;
    A = wsu + FBC + (size_t)t2 * 1280000; Bt = wsu + WTCS + (size_t)t2 * 32768;
    bias = bcs + (size_t)t2 * HD; C = wsu + WHB_CS + (size_t)t2 * NC * HD; M = NC; K = 128;
    nrel = 1; sout[0] = wsf + ASCS + (size_t)t2 * NC * H_; avec[0] = acsv + (size_t)t2 * 512;
  } else if (z == 12) {
    A = wsu + FBS; Bt = wsu + WTIN; bias = bin; C = wsu + WHB_IN; M = NS; K = 64;
    nrel = 3;
    for (int j = 0; j < 3; j++) {
      sout[j] = wsf + ADCS + (size_t)j * NS * H_;
      avec[j] = acsv + (size_t)j * 512 + 256;
    }
  } else {
    int d = z - 13;
    A = wsu + FBC + (size_t)d * 1280000; Bt = wsu + WTN + (size_t)d * 32768;
    bias = bnode + (size_t)d * HD; C = nullptr; M = NC; K = 128; storeC = false;
    nrel = 3;
    for (int j = 0; j < 3; j++) {
      int r = 3 * j + d;
      sout[j] = wsf + ADCC + (size_t)r * NC * H_;
      avec[j] = accv + (size_t)r * 512 + 256;
    }
  }
  int r0 = blockIdx.x * 128; if (r0 >= M) return;
  int n0 = blockIdx.y * 128;
  int t = threadIdx.x;
  int SA = K + 8;
  {
    int ksh = (K == 128) ? 4 : 3;
    int kmask = (1 << ksh) - 1;
    int sc8 = SA >> 3;
    const uint4* ga = (const uint4*)(A + (size_t)r0 * K);
    const uint4* gb = (const uint4*)(Bt + (size_t)n0 * K);
    uint4* la = (uint4*)As; uint4* lb = (uint4*)Bs;
    int tot = (128 * K) >> 3;
    for (int i = t; i < tot; i += 256) la[(i >> ksh) * sc8 + (i & kmask)] = ga[i];
    for (int i = t; i < tot; i += 256) lb[(i >> ksh) * sc8 + (i & kmask)] = gb[i];
  }
  __syncthreads();
  int lane = t & 63, w = t >> 6, l16 = lane & 15, quad = lane >> 4;
  f32x4 acc[2][8];
  #pragma unroll
  for (int i = 0; i < 2; i++)
    #pragma unroll
    for (int j = 0; j < 8; j++) acc[i][j] = (f32x4){0.f, 0.f, 0.f, 0.f};
  int arow0 = w * 32 + l16;
  for (int ks = 0; ks < K; ks += 32) {
    int ko = ks + quad * 8;
    short8 a0 = *(const short8*)&As[(size_t)arow0 * SA + ko];
    short8 a1 = *(const short8*)&As[(size_t)(arow0 + 16) * SA + ko];
    #pragma unroll
    for (int j = 0; j < 8; j++) {
      short8 bfr = *(const short8*)&Bs[(size_t)(j * 16 + l16) * SA + ko];
      acc[0][j] = __builtin_amdgcn_mfma_f32_16x16x32_bf16(a0, bfr, acc[0][j], 0, 0, 0);
      acc[1][j] = __builtin_amdgcn_mfma_f32_16x16x32_bf16(a1, bfr, acc[1][j], 0, 0, 0);
    }
  }
  __syncthreads();
  float* Cl = (float*)smem;              // 128 x 129 f32 tile
  float* Al = (float*)(smem + 66048);    // up to 3*128 attn floats
  int hb = n0 >> 5;
  for (int i = t; i < nrel * 128; i += 256) {
    int rel = i >> 7, q = i & 127;
    Al[i] = avec[rel][hb * 32 + q];
  }
  #pragma unroll
  for (int i = 0; i < 2; i++) {
    int rl0 = w * 32 + i * 16 + quad * 4;
    #pragma unroll
    for (int j = 0; j < 8; j++) {
      int cl = j * 16 + l16;
      float bv = bias[n0 + cl];
      #pragma unroll
      for (int rg = 0; rg < 4; rg++) {
        float v = acc[i][j][rg] + bv;
        Cl[(rl0 + rg) * 129 + cl] = v;
        int grow = r0 + rl0 + rg;
        if (storeC && grow < M) C[(size_t)grow * HD + n0 + cl] = f2b(v);
      }
    }
  }
  __syncthreads();
  int row = t >> 1, pr = t & 1;
  int gr = r0 + row;
  const float* cp = Cl + row * 129 + pr * 64;
  for (int rel = 0; rel < nrel; rel++) {
    const float* ap = Al + rel * 128 + pr * 64;
    float d0 = 0.f, d1 = 0.f;
    #pragma unroll
    for (int d = 0; d < 32; d++) {
      d0 += cp[d] * ap[d];
      d1 += cp[32 + d] * ap[32 + d];
    }
    if (gr < M) *(float2*)&sout[rel][(size_t)gr * 8 + hb + 2 * pr] = make_float2(d0, d1);
  }
}

// ================= K3: aggregation, 1 wave/node, 4 edges/iter =================
__global__ __launch_bounds__(256) void k_agg(const u16* wsu, const float* wsf,
                                             const int* cnts, const u16* slt,
                                             float* out) {
  int t = threadIdx.x, lane = t & 63, w = t >> 6;
  int node = blockIdx.x * 4 + w;
  int g = lane >> 4, lq = lane & 15, h = lq >> 1;
  float acc[16];
  #pragma unroll
  for (int q = 0; q < 16; q++) acc[q] = 0.f;
  bool isC = node < 3 * NC;
  int dtype = 0, n;
  if (isC) { dtype = node / NC; n = node - dtype * NC; } else { n = node - 3 * NC; }
  for (int j = 0; j < 3; j++) {
    int cidx; size_t slotb; const float* ASp; float adn; const u16* whb;
    if (isC) {
      int r = j * 3 + dtype;
      cidx  = r * NC + n;
      slotb = ((size_t)(r * NC + n)) * CAP;
      ASp   = wsf + ASCC + (size_t)r * NC * H_;
      adn   = wsf[ADCC + (size_t)r * NC * H_ + (size_t)n * H_ + h];
      whb   = wsu + WHB_CC + (size_t)r * NC * HD;
    } else {
      int r = j;
      cidx  = 90000 + r * NS + n;
      slotb = SLOTCS16 + ((size_t)(r * NS + n)) * CAP;
      ASp   = wsf + ASCS + (size_t)r * NC * H_;
      adn   = wsf[ADCS + (size_t)r * NS * H_ + (size_t)n * H_ + h];
      whb   = wsu + WHB_CS + (size_t)r * NC * HD;
    }
    int cnt = cnts[cidx];
    cnt = min(cnt, CAP);
    if (cnt <= 0) continue;
    int vsrc = (int)slt[slotb + min(lane, cnt - 1)];
    float a[16];
    #pragma unroll
    for (int q = 0; q < 16; q++) a[q] = 0.f;
    float sH = 0.f;
    for (int e = 0; e < cnt; e += 4) {
      int idx = min(e + g, cnt - 1);
      int so = __shfl(vsrc, idx);
      float sc = *(const float*)((const char*)ASp + ((size_t)so << 5) + (h << 2)) + adn;
      sc = fmaxf(sc, ALPHA * sc);
      float wgt = (e + g < cnt) ? __expf(sc) : 0.f;
      const char* wrow = (const char*)whb + ((size_t)so << 9) + lq * 32;
      uint4 m0 = *(const uint4*)wrow;
      uint4 m1 = *(const uint4*)(wrow + 16);
      a[0]  += wgt * bl(m0.x); a[1]  += wgt * bh(m0.x);
      a[2]  += wgt * bl(m0.y); a[3]  += wgt * bh(m0.y);
      a[4]  += wgt * bl(m0.z); a[5]  += wgt * bh(m0.z);
      a[6]  += wgt * bl(m0.w); a[7]  += wgt * bh(m0.w);
      a[8]  += wgt * bl(m1.x); a[9]  += wgt * bh(m1.x);
      a[10] += wgt * bl(m1.y); a[11] += wgt * bh(m1.y);
      a[12] += wgt * bl(m1.z); a[13] += wgt * bh(m1.z);
      a[14] += wgt * bl(m1.w); a[15] += wgt * bh(m1.w);
      sH += wgt;
    }
    sH += __shfl_xor(sH, 16);
    sH += __shfl_xor(sH, 32);
    float inv = 1.f / sH;
    #pragma unroll
    for (int q = 0; q < 16; q++) acc[q] += a[q] * inv;
  }
  #pragma unroll
  for (int q = 0; q < 16; q++) {
    acc[q] += __shfl_xor(acc[q], 16);
    acc[q] += __shfl_xor(acc[q], 32);
  }
  if (!isC) {
    // add self term to the 4 elements this lane writes: [lq*16 + g*4, +4)
    uint2 m = *(const uint2*)((const char*)(wsu + WHB_IN) + (size_t)n * 512 + lq * 32 + g * 8);
    acc[g * 4 + 0] += bl(m.x); acc[g * 4 + 1] += bh(m.x);
    acc[g * 4 + 2] += bl(m.y); acc[g * 4 + 3] += bh(m.y);
  }
  float4 v = make_float4(acc[g * 4 + 0], acc[g * 4 + 1], acc[g * 4 + 2], acc[g * 4 + 3]);
  v.x = fmaxf(v.x, 0.f); v.y = fmaxf(v.y, 0.f);
  v.z = fmaxf(v.z, 0.f); v.w = fmaxf(v.w, 0.f);
  *(float4*)(out + (size_t)node * HD + lq * 16 + g * 4) = v;
}

extern "C" void kernel_launch(void* const* d_in, const int* in_sizes, int n_in,
                              void* d_out, int out_size, void* d_ws, size_t ws_size,
                              hipStream_t stream) {
  (void)in_sizes; (void)n_in; (void)out_size; (void)ws_size;
  const float* f1    = (const float*)d_in[0];
  const float* f2    = (const float*)d_in[1];
  const float* f3    = (const float*)d_in[2];
  const float* fs    = (const float*)d_in[3];
  const float* Wnode = (const float*)d_in[4];
  const float* bnode = (const float*)d_in[5];
  const float* Wcc   = (const float*)d_in[6];
  const float* bcc   = (const float*)d_in[7];
  const float* Wcs   = (const float*)d_in[8];
  const float* bcs   = (const float*)d_in[9];
  const float* Win   = (const float*)d_in[10];
  const float* bin   = (const float*)d_in[11];
  const float* accv  = (const float*)d_in[12];
  const float* acsv  = (const float*)d_in[13];
  const int* eccs    = (const int*)d_in[14];
  const int* eccd    = (const int*)d_in[15];
  const int* ecss    = (const int*)d_in[16];
  const int* ecsd    = (const int*)d_in[17];
  float* wsf = (float*)d_ws;
  u16*   wsu = (u16*)d_ws;
  int*   cnts = (int*)((char*)d_ws + IBYTE);
  u16*   slt  = (u16*)((char*)d_ws + SBYTE);
  float* out = (float*)d_out;

  hipMemsetAsync((char*)d_ws + IBYTE, 0, 93072 * 4, stream);
  k_prep<<<dim3(NB_SC + NB_FT + NB_WT), 256, 0, stream>>>(
      f1, f2, f3, fs, Wcc, Wcs, Win, Wnode, eccs, eccd, ecss, ecsd,
      wsu, cnts, slt);
  k_gemmb<<<dim3(79, 2, 16), 256, 0, stream>>>(
      wsu, wsf, bcc, bcs, bin, bnode, accv, acsv);
  k_agg<<<dim3((3 * NC + NS) / 4), 256, 0, stream>>>(wsu, wsf, cnts, slt, out);
}

// Round 7
// 321.139 us; speedup vs baseline: 1.0089x; 1.0089x over previous
//
#include <hip/hip_runtime.h>

// HeteroGAT on MI355X. R7:
//   K1 k_cvt: zero counters + feat f32->bf16 + weight transpose (LDS tiles)
//   K2 k_gemmb: 542 scatter blocks (fabric-latency-bound, dispatched first)
//               fused with 2528 bf16-MFMA GEMM blocks (compute-bound) -> overlap
//   K3 k_agg: 1 wave/dst node, R5 lane mapping, 4-edge software pipeline

#define H_ 8
#define D_ 32
#define HD 256
#define NC 10000
#define NS 1024
#define INC 128
#define INS 64
#define ECC 120000
#define ECS 10000
#define ALPHA 0.2f
#define CAP 64

typedef unsigned short u16;
typedef __attribute__((ext_vector_type(8))) short short8;
typedef __attribute__((ext_vector_type(4))) float f32x4;

// ---- ws layout ----
// u16 region (u16 units)
static constexpr size_t WHB_CC = 0;              // 9*NC*HD
static constexpr size_t WHB_CS = 23040000;       // 3*NC*HD
static constexpr size_t WHB_IN = 30720000;       // NS*HD -> end 30982144 u16
// f32 scores (float units)
static constexpr size_t FB0  = 15491072;
static constexpr size_t ASCC = FB0;              // 9*NC*8
static constexpr size_t ADCC = FB0 + 720000;     // 9*NC*8
static constexpr size_t ASCS = FB0 + 1440000;    // 3*NC*8
static constexpr size_t ADCS = FB0 + 1680000;    // 3*NS*8
// bf16 feats + transposed weights (u16 units)
static constexpr size_t FBC  = 34437760;         // 3*NC*128
static constexpr size_t FBS  = 38277760;         // NS*64
static constexpr size_t WTCC = 38343296;         // 9*32768
static constexpr size_t WTCS = 38638208;         // 3*32768
static constexpr size_t WTIN = 38736512;         // 256*64
static constexpr size_t WTN  = 38752896;         // 3*32768 -> end 38851200 u16
// int counters (byte offset): 93072 ints = 9*NC (cc) then 3*NS (cs)
static constexpr size_t IBYTE = 77702400;
// u16 slots (byte offset): slot for counter c is slt[c*CAP ...] (cs follows cc exactly)
static constexpr size_t SBYTE = 78074688;

static constexpr int TOTE  = 9 * ECC + 3 * ECS;  // 1,110,000 (divisible by 8)
static constexpr int NB_SC = 542;                // ceil(TOTE/2048)
static constexpr int NB_Z0 = 91;                 // zero: 93072 ints / int4 / 256
static constexpr int NB_FT = 3814;
static constexpr int NB_WT = 128;
static constexpr int NB_GE = 2528;               // 79 x * 2 y * 16 z

__device__ __forceinline__ u16 f2b(float f) {
  unsigned u = __float_as_uint(f);
  return (u16)((u + 0x7FFFu + ((u >> 16) & 1u)) >> 16);
}
__device__ __forceinline__ float bl(unsigned u) { return __uint_as_float(u << 16); }
__device__ __forceinline__ float bh(unsigned u) { return __uint_as_float(u & 0xffff0000u); }

// ================= K1: zero + cvt_feat + cvt_w(LDS transpose) =================
__global__ __launch_bounds__(256) void k_cvt(
    const float* f1, const float* f2, const float* f3, const float* fs,
    const float* Wcc, const float* Wcs, const float* Win, const float* Wnode,
    u16* wsu, int* cnts) {
  __shared__ float Ls[64 * 65];
  int b = blockIdx.x, t = threadIdx.x;
  if (b < NB_Z0) {                                 // ---- zero counters ----
    int i = b * 256 + t;
    if (i < 23268) ((int4*)cnts)[i] = make_int4(0, 0, 0, 0);
    return;
  }
  b -= NB_Z0;
  if (b < NB_FT) {                                 // ---- f32 -> bf16 feats ----
    const float* src; u16* dst; int idx, n4;
    if (b < 3750) {
      int ty = b / 1250;
      src = (ty == 0) ? f1 : (ty == 1) ? f2 : f3;
      dst = wsu + FBC + (size_t)ty * 1280000;
      idx = (b - ty * 1250) * 256 + t; n4 = 320000;
    } else {
      src = fs; dst = wsu + FBS; idx = (b - 3750) * 256 + t; n4 = 16384;
    }
    if (idx < n4) {
      float4 v = ((const float4*)src)[idx];
      uint2 o;
      o.x = (unsigned)f2b(v.x) | ((unsigned)f2b(v.y) << 16);
      o.y = (unsigned)f2b(v.z) | ((unsigned)f2b(v.w) << 16);
      *(uint2*)(dst + (size_t)idx * 4) = o;
    }
    return;
  }
  b -= NB_FT;                                      // ---- weight transpose, LDS tile ----
  int mat = b >> 3, sub = b & 7;
  int K = (mat == 12) ? INS : INC;
  if (mat == 12 && sub >= 4) return;
  int k0 = (sub >> 2) * 64, n0 = (sub & 3) * 64;
  const float* src; u16* dst;
  if (mat < 9)        { src = Wcc + (size_t)mat * INC * HD;          dst = wsu + WTCC + (size_t)mat * 32768; }
  else if (mat < 12)  { src = Wcs + (size_t)(mat - 9) * INC * HD;    dst = wsu + WTCS + (size_t)(mat - 9) * 32768; }
  else if (mat == 12) { src = Win;                                   dst = wsu + WTIN; }
  else                { src = Wnode + (size_t)(mat - 13) * INC * HD; dst = wsu + WTN + (size_t)(mat - 13) * 32768; }
  #pragma unroll
  for (int it = 0; it < 4; it++) {
    int idx = t + it * 256;
    int r = idx >> 4, c4 = idx & 15;
    float4 v = *(const float4*)&src[(size_t)(k0 + r) * HD + n0 + c4 * 4];
    Ls[r * 65 + c4 * 4 + 0] = v.x; Ls[r * 65 + c4 * 4 + 1] = v.y;
    Ls[r * 65 + c4 * 4 + 2] = v.z; Ls[r * 65 + c4 * 4 + 3] = v.w;
  }
  __syncthreads();
  int n = t >> 2, k8 = (t & 3) * 16;
  unsigned o[8];
  #pragma unroll
  for (int j = 0; j < 8; j++) {
    u16 lo = f2b(Ls[(k8 + 2 * j) * 65 + n]);
    u16 hi = f2b(Ls[(k8 + 2 * j + 1) * 65 + n]);
    o[j] = (unsigned)lo | ((unsigned)hi << 16);
  }
  uint4* dp = (uint4*)&dst[(size_t)(n0 + n) * K + k0 + k8];
  dp[0] = make_uint4(o[0], o[1], o[2], o[3]);
  dp[1] = make_uint4(o[4], o[5], o[6], o[7]);
}

// ================= K2: scatter (first) + 16 GEMMs w/ score epilogue =================
__global__ __launch_bounds__(256, 2) void k_gemmb(
    u16* wsu, float* wsf, const float* bcc, const float* bcs, const float* bin,
    const float* bnode, const float* accv, const float* acsv,
    const int* eccs, const int* eccd, const int* ecss, const int* ecsd,
    int* cnts, u16* slt) {
  __shared__ __align__(16) char smem[69632];
  int b = blockIdx.x, t = threadIdx.x;
  if (b < NB_SC) {                                 // ---- edge scatter, 8/thread ----
    int i0 = (b * 256 + t) * 8;
    if (i0 >= TOTE) return;
    int dd[8], ss[8], p[8];
    int cbase;
    if (i0 < 9 * ECC) {
      int r = i0 / ECC;
      int4 d0 = *(const int4*)&eccd[i0]; int4 d1 = *(const int4*)&eccd[i0 + 4];
      int4 s0 = *(const int4*)&eccs[i0]; int4 s1 = *(const int4*)&eccs[i0 + 4];
      dd[0]=d0.x; dd[1]=d0.y; dd[2]=d0.z; dd[3]=d0.w;
      dd[4]=d1.x; dd[5]=d1.y; dd[6]=d1.z; dd[7]=d1.w;
      ss[0]=s0.x; ss[1]=s0.y; ss[2]=s0.z; ss[3]=s0.w;
      ss[4]=s1.x; ss[5]=s1.y; ss[6]=s1.z; ss[7]=s1.w;
      cbase = r * NC;
    } else {
      int u0 = i0 - 9 * ECC;
      int r = u0 / ECS;
      int4 d0 = *(const int4*)&ecsd[u0]; int4 d1 = *(const int4*)&ecsd[u0 + 4];
      int4 s0 = *(const int4*)&ecss[u0]; int4 s1 = *(const int4*)&ecss[u0 + 4];
      dd[0]=d0.x; dd[1]=d0.y; dd[2]=d0.z; dd[3]=d0.w;
      dd[4]=d1.x; dd[5]=d1.y; dd[6]=d1.z; dd[7]=d1.w;
      ss[0]=s0.x; ss[1]=s0.y; ss[2]=s0.z; ss[3]=s0.w;
      ss[4]=s1.x; ss[5]=s1.y; ss[6]=s1.z; ss[7]=s1.w;
      cbase = 90000 + r * NS;
    }
    #pragma unroll
    for (int q = 0; q < 8; q++) p[q] = atomicAdd(&cnts[cbase + dd[q]], 1);
    #pragma unroll
    for (int q = 0; q < 8; q++)
      if (p[q] < CAP) slt[((size_t)(cbase + dd[q])) * CAP + p[q]] = (u16)ss[q];
    return;
  }
  // ---- gemm ----
  int g = b - NB_SC;
  int z = g / 158, rem = g - z * 158;
  int by = rem / 79, bx = rem - by * 79;
  u16* As = (u16*)smem;
  u16* Bs = (u16*)(smem + 34816);
  const u16 *A, *Bt; const float* bias; u16* C; int M, K;
  int nrel; float* sout[3]; const float* avec[3]; bool storeC = true;
  if (z < 9) {
    A = wsu + FBC + (size_t)(z / 3) * 1280000; Bt = wsu + WTCC + (size_t)z * 32768;
    bias = bcc + (size_t)z * HD; C = wsu + WHB_CC + (size_t)z * NC * HD; M = NC; K = 128;
    nrel = 1; sout[0] = wsf + ASCC + (size_t)z * NC * H_; avec[0] = accv + (size_t)z * 512;
  } else if (z < 12) {
    int t2 = z - 9;
    A = wsu + FBC + (size_t)t2 * 1280000; Bt = wsu + WTCS + (size_t)t2 * 32768;
    bias = bcs + (size_t)t2 * HD; C = wsu + WHB_CS + (size_t)t2 * NC * HD; M = NC; K = 128;
    nrel = 1; sout[0] = wsf + ASCS + (size_t)t2 * NC * H_; avec[0] = acsv + (size_t)t2 * 512;
  } else if (z == 12) {
    A = wsu + FBS; Bt = wsu + WTIN; bias = bin; C = wsu + WHB_IN; M = NS; K = 64;
    nrel = 3;
    for (int j = 0; j < 3; j++) {
      sout[j] = wsf + ADCS + (size_t)j * NS * H_;
      avec[j] = acsv + (size_t)j * 512 + 256;
    }
  } else {
    int d = z - 13;
    A = wsu + FBC + (size_t)d * 1280000; Bt = wsu + WTN + (size_t)d * 32768;
    bias = bnode + (size_t)d * HD; C = nullptr; M = NC; K = 128; storeC = false;
    nrel = 3;
    for (int j = 0; j < 3; j++) {
      int r = 3 * j + d;
      sout[j] = wsf + ADCC + (size_t)r * NC * H_;
      avec[j] = accv + (size_t)r * 512 + 256;
    }
  }
  int r0 = bx * 128; if (r0 >= M) return;
  int n0 = by * 128;
  int SA = K + 8;
  {
    int ksh = (K == 128) ? 4 : 3;
    int kmask = (1 << ksh) - 1;
    int sc8 = SA >> 3;
    const uint4* ga = (const uint4*)(A + (size_t)r0 * K);
    const uint4* gb = (const uint4*)(Bt + (size_t)n0 * K);
    uint4* la = (uint4*)As; uint4* lb = (uint4*)Bs;
    int tot = (128 * K) >> 3;
    for (int i = t; i < tot; i += 256) la[(i >> ksh) * sc8 + (i & kmask)] = ga[i];
    for (int i = t; i < tot; i += 256) lb[(i >> ksh) * sc8 + (i & kmask)] = gb[i];
  }
  __syncthreads();
  int lane = t & 63, w = t >> 6, l16 = lane & 15, quad = lane >> 4;
  f32x4 acc[2][8];
  #pragma unroll
  for (int i = 0; i < 2; i++)
    #pragma unroll
    for (int j = 0; j < 8; j++) acc[i][j] = (f32x4){0.f, 0.f, 0.f, 0.f};
  int arow0 = w * 32 + l16;
  for (int ks = 0; ks < K; ks += 32) {
    int ko = ks + quad * 8;
    short8 a0 = *(const short8*)&As[(size_t)arow0 * SA + ko];
    short8 a1 = *(const short8*)&As[(size_t)(arow0 + 16) * SA + ko];
    #pragma unroll
    for (int j = 0; j < 8; j++) {
      short8 bfr = *(const short8*)&Bs[(size_t)(j * 16 + l16) * SA + ko];
      acc[0][j] = __builtin_amdgcn_mfma_f32_16x16x32_bf16(a0, bfr, acc[0][j], 0, 0, 0);
      acc[1][j] = __builtin_amdgcn_mfma_f32_16x16x32_bf16(a1, bfr, acc[1][j], 0, 0, 0);
    }
  }
  __syncthreads();
  float* Cl = (float*)smem;              // 128 x 129 f32 tile
  float* Al = (float*)(smem + 66048);    // up to 3*128 attn floats
  int hb = n0 >> 5;
  for (int i = t; i < nrel * 128; i += 256) {
    int rel = i >> 7, q = i & 127;
    Al[i] = avec[rel][hb * 32 + q];
  }
  #pragma unroll
  for (int i = 0; i < 2; i++) {
    int rl0 = w * 32 + i * 16 + quad * 4;
    #pragma unroll
    for (int j = 0; j < 8; j++) {
      int cl = j * 16 + l16;
      float bv = bias[n0 + cl];
      #pragma unroll
      for (int rg = 0; rg < 4; rg++) {
        float v = acc[i][j][rg] + bv;
        Cl[(rl0 + rg) * 129 + cl] = v;
        int grow = r0 + rl0 + rg;
        if (storeC && grow < M) C[(size_t)grow * HD + n0 + cl] = f2b(v);
      }
    }
  }
  __syncthreads();
  int row = t >> 1, pr = t & 1;
  int gr = r0 + row;
  const float* cp = Cl + row * 129 + pr * 64;
  for (int rel = 0; rel < nrel; rel++) {
    const float* ap = Al + rel * 128 + pr * 64;
    float d0 = 0.f, d1 = 0.f;
    #pragma unroll
    for (int d = 0; d < 32; d++) {
      d0 += cp[d] * ap[d];
      d1 += cp[32 + d] * ap[32 + d];
    }
    if (gr < M) *(float2*)&sout[rel][(size_t)gr * 8 + hb + 2 * pr] = make_float2(d0, d1);
  }
}

// ================= K3: aggregation, 1 wave/dst node, 4-edge pipeline =================
__global__ __launch_bounds__(256) void k_agg(const u16* wsu, const float* wsf,
                                             const int* cnts, const u16* slt,
                                             float* out) {
  int t = threadIdx.x, lane = t & 63, w = t >> 6;
  int node = blockIdx.x * 4 + w;
  int sub = lane & 31, half = lane >> 5, h = sub >> 2;
  float acc[8] = {0.f, 0.f, 0.f, 0.f, 0.f, 0.f, 0.f, 0.f};
  bool isC = node < 3 * NC;
  int dtype = 0, n;
  if (isC) { dtype = node / NC; n = node - dtype * NC; } else { n = node - 3 * NC; }
  for (int j = 0; j < 3; j++) {
    int cidx; const float* ASp; float adn; const u16* whb;
    if (isC) {
      int r = j * 3 + dtype;
      cidx = r * NC + n;
      ASp  = wsf + ASCC + (size_t)r * NC * H_;
      adn  = wsf[ADCC + (size_t)r * NC * H_ + (size_t)n * H_ + h];
      whb  = wsu + WHB_CC + (size_t)r * NC * HD;
    } else {
      int r = j;
      cidx = 90000 + r * NS + n;
      ASp  = wsf + ASCS + (size_t)r * NC * H_;
      adn  = wsf[ADCS + (size_t)r * NS * H_ + (size_t)n * H_ + h];
      whb  = wsu + WHB_CS + (size_t)r * NC * HD;
    }
    int cnt = cnts[cidx];
    cnt = min(cnt, CAP);
    if (cnt <= 0) continue;
    int vsrc = ((int)slt[(size_t)cidx * CAP + min(lane, cnt - 1)]) << 5;  // src*32 B
    const char* sb_ = (const char*)ASp + h * 4;
    const char* wb_ = (const char*)whb + sub * 16;
    float a8[8] = {0.f, 0.f, 0.f, 0.f, 0.f, 0.f, 0.f, 0.f};
    float sH = 0.f;
    for (int e = 0; e < cnt; e += 4) {
      int i0 = min(e + half, cnt - 1);
      int i1 = min(e + 2 + half, cnt - 1);
      int so0 = __shfl(vsrc, i0);
      int so1 = __shfl(vsrc, i1);
      float sc0 = *(const float*)(sb_ + so0) + adn;
      float sc1 = *(const float*)(sb_ + so1) + adn;
      uint4 m0 = *(const uint4*)(wb_ + ((size_t)so0 << 4));
      uint4 m1 = *(const uint4*)(wb_ + ((size_t)so1 << 4));
      sc0 = fmaxf(sc0, ALPHA * sc0);
      sc1 = fmaxf(sc1, ALPHA * sc1);
      float w0 = (e + half < cnt) ? __expf(sc0) : 0.f;
      float w1 = (e + 2 + half < cnt) ? __expf(sc1) : 0.f;
      a8[0] += w0 * bl(m0.x); a8[1] += w0 * bh(m0.x);
      a8[2] += w0 * bl(m0.y); a8[3] += w0 * bh(m0.y);
      a8[4] += w0 * bl(m0.z); a8[5] += w0 * bh(m0.z);
      a8[6] += w0 * bl(m0.w); a8[7] += w0 * bh(m0.w);
      a8[0] += w1 * bl(m1.x); a8[1] += w1 * bh(m1.x);
      a8[2] += w1 * bl(m1.y); a8[3] += w1 * bh(m1.y);
      a8[4] += w1 * bl(m1.z); a8[5] += w1 * bh(m1.z);
      a8[6] += w1 * bl(m1.w); a8[7] += w1 * bh(m1.w);
      sH += w0 + w1;
    }
    sH += __shfl_xor(sH, 32);
    float inv = 1.f / sH;
    #pragma unroll
    for (int q = 0; q < 8; q++) acc[q] += a8[q] * inv;
  }
  #pragma unroll
  for (int q = 0; q < 8; q++) acc[q] += __shfl_xor(acc[q], 32);
  if (!isC) {
    uint4 m = *(const uint4*)((const char*)(wsu + WHB_IN) + (size_t)n * 512 + sub * 16);
    acc[0] += bl(m.x); acc[1] += bh(m.x); acc[2] += bl(m.y); acc[3] += bh(m.y);
    acc[4] += bl(m.z); acc[5] += bh(m.z); acc[6] += bl(m.w); acc[7] += bh(m.w);
  }
  float4 v;
  if (half == 0) v = make_float4(acc[0], acc[1], acc[2], acc[3]);
  else           v = make_float4(acc[4], acc[5], acc[6], acc[7]);
  v.x = fmaxf(v.x, 0.f); v.y = fmaxf(v.y, 0.f);
  v.z = fmaxf(v.z, 0.f); v.w = fmaxf(v.w, 0.f);
  *(float4*)(out + (size_t)node * HD + sub * 8 + half * 4) = v;
}

extern "C" void kernel_launch(void* const* d_in, const int* in_sizes, int n_in,
                              void* d_out, int out_size, void* d_ws, size_t ws_size,
                              hipStream_t stream) {
  (void)in_sizes; (void)n_in; (void)out_size; (void)ws_size;
  const float* f1    = (const float*)d_in[0];
  const float* f2    = (const float*)d_in[1];
  const float* f3    = (const float*)d_in[2];
  const float* fs    = (const float*)d_in[3];
  const float* Wnode = (const float*)d_in[4];
  const float* bnode = (const float*)d_in[5];
  const float* Wcc   = (const float*)d_in[6];
  const float* bcc   = (const float*)d_in[7];
  const float* Wcs   = (const float*)d_in[8];
  const float* bcs   = (const float*)d_in[9];
  const float* Win   = (const float*)d_in[10];
  const float* bin   = (const float*)d_in[11];
  const float* accv  = (const float*)d_in[12];
  const float* acsv  = (const float*)d_in[13];
  const int* eccs    = (const int*)d_in[14];
  const int* eccd    = (const int*)d_in[15];
  const int* ecss    = (const int*)d_in[16];
  const int* ecsd    = (const int*)d_in[17];
  float* wsf = (float*)d_ws;
  u16*   wsu = (u16*)d_ws;
  int*   cnts = (int*)((char*)d_ws + IBYTE);
  u16*   slt  = (u16*)((char*)d_ws + SBYTE);
  float* out = (float*)d_out;

  k_cvt<<<dim3(NB_Z0 + NB_FT + NB_WT), 256, 0, stream>>>(
      f1, f2, f3, fs, Wcc, Wcs, Win, Wnode, wsu, cnts);
  k_gemmb<<<dim3(NB_SC + NB_GE), 256, 0, stream>>>(
      wsu, wsf, bcc, bcs, bin, bnode, accv, acsv,
      eccs, eccd, ecss, ecsd, cnts, slt);
  k_agg<<<dim3((3 * NC + NS) / 4), 256, 0, stream>>>(wsu, wsf, cnts, slt, out);
}